// Round 1
// baseline (1175.000 us; speedup 1.0000x reference)
//
#include <hip/hip_runtime.h>
#include <math.h>

// Problem constants (from reference): B=64, N=512, T=6, H=4, E=256, hd=64
#define TT 6
#define HH 4
#define EE 256
#define HDIM 64
#define GG 8            // chunks (bn groups) per block
#define NTHREADS 256

__device__ __forceinline__ float wave64_reduce(float v) {
    v += __shfl_xor(v, 32, 64);
    v += __shfl_xor(v, 16, 64);
    v += __shfl_xor(v, 8, 64);
    v += __shfl_xor(v, 4, 64);
    v += __shfl_xor(v, 2, 64);
    v += __shfl_xor(v, 1, 64);
    return v;
}

__device__ __forceinline__ float group16_reduce(float v) {
    v += __shfl_xor(v, 8, 64);
    v += __shfl_xor(v, 4, 64);
    v += __shfl_xor(v, 2, 64);
    v += __shfl_xor(v, 1, 64);
    return v;
}

// Precompute q = query@Wq.T + bq, then fold q into Wk:
//   s_w[h][e] = sum_d q[h*64+d] * Wk[h*64+d][e]
//   s_b[h]    = sum_d q[h*64+d] * bk[h*64+d]
__global__ void setup_kernel(const float* __restrict__ query,
                             const float* __restrict__ in_proj_w,
                             const float* __restrict__ in_proj_b,
                             float* __restrict__ s_w,   // [H*E]
                             float* __restrict__ s_b)   // [H]
{
    __shared__ float q[EE];
    int tid = threadIdx.x;
    {
        float acc = in_proj_b[tid];
        const float* row = in_proj_w + (size_t)tid * EE;  // Wq row tid
        for (int e = 0; e < EE; ++e) acc += query[e] * row[e];
        q[tid] = acc;
    }
    __syncthreads();
    int ep = tid;
    for (int h = 0; h < HH; ++h) {
        float acc = 0.f;
        for (int d = 0; d < HDIM; ++d) {
            // Wk row (E + h*64 + d), column ep  -> coalesced across threads
            acc += q[h * HDIM + d] * in_proj_w[(size_t)(EE + h * HDIM + d) * EE + ep];
        }
        s_w[h * EE + ep] = acc;
    }
    if (tid < HH) {
        float acc = 0.f;
        for (int d = 0; d < HDIM; ++d)
            acc += q[tid * HDIM + d] * in_proj_b[EE + tid * HDIM + d];
        s_b[tid] = acc;
    }
}

__global__ __launch_bounds__(NTHREADS)
void fused_head_kernel(const float* __restrict__ x,
                       const int* __restrict__ mask,
                       const float* __restrict__ in_proj_w,
                       const float* __restrict__ in_proj_b,
                       const float* __restrict__ out_w,
                       const float* __restrict__ out_b,
                       const float* __restrict__ ln_g,
                       const float* __restrict__ ln_b,
                       const float* __restrict__ w1,
                       const float* __restrict__ b1,
                       const float* __restrict__ w2,
                       const float* __restrict__ b2,
                       const float* __restrict__ s_w,
                       const float* __restrict__ s_b,
                       float* __restrict__ out)
{
    __shared__ float sw_s[HH * EE];        // 4 KB  folded score weights
    __shared__ float sb_s[HH];
    __shared__ float xbuf[TT * EE];        // 6 KB  one chunk's x
    __shared__ int   mbuf[TT];
    __shared__ float sc[HH * TT];          // scores
    __shared__ float aw[HH * TT];          // attention weights
    __shared__ float validf[GG];
    __shared__ float xbar[GG][HH * EE];    // 32 KB weighted token avgs (per head)
    __shared__ float ypre[GG][EE];         // 8 KB  attn (Wv stage), reused for LN output
    __shared__ float outv[GG][EE];         // 8 KB  out-proj output
    __shared__ float hbuf[GG][EE / 2];     // 4 KB  gelu(mlp1)

    const int tid  = threadIdx.x;
    const int wave = tid >> 6;
    const int lane = tid & 63;
    const int q4   = lane >> 4;    // sub-group 0..3 (row within quad)
    const int li   = lane & 15;    // lane within 16-group
    const int chunk0 = blockIdx.x * GG;

    // load folded score weights once
    for (int i = tid; i < HH * EE; i += NTHREADS) sw_s[i] = s_w[i];
    if (tid < HH) sb_s[tid] = s_b[tid];

    // ---------- Phase 1: scores -> softmax -> xbar, per chunk ----------
    for (int g = 0; g < GG; ++g) {
        const int bn = chunk0 + g;
        const float* xc = x + (size_t)bn * (TT * EE);
        __syncthreads();   // prev iteration consumers of xbuf/aw done; also sw_s ready (g=0)
        for (int i = tid; i < TT * EE; i += NTHREADS) xbuf[i] = xc[i];
        if (tid < TT) mbuf[tid] = mask[(size_t)bn * TT + tid];
        __syncthreads();

        // scores: 24 (h,t) pairs, 6 per wave; full-wave dot over E=256
        for (int i = 0; i < 6; ++i) {
            int p = wave * 6 + i;        // 0..23
            int h = p / TT, t = p % TT;
            float part = 0.f;
#pragma unroll
            for (int k = 0; k < 4; ++k) {
                int e = lane + 64 * k;
                part += sw_s[h * EE + e] * xbuf[t * EE + e];
            }
            float s = wave64_reduce(part);
            if (lane == 0) sc[h * TT + t] = (s + sb_s[h]) * 0.125f;  // /sqrt(64)
        }
        __syncthreads();

        // softmax per head (threads 0..3); valid flag (thread 0)
        if (tid < HH) {
            float vsc[TT];
            float m = -INFINITY;
            for (int t = 0; t < TT; ++t) {
                float v = mbuf[t] ? sc[tid * TT + t] : -1e9f;
                vsc[t] = v;
                m = fmaxf(m, v);
            }
            float sum = 0.f;
            for (int t = 0; t < TT; ++t) {
                float e = expf(vsc[t] - m);
                aw[tid * TT + t] = e;
                sum += e;
            }
            float inv = 1.f / sum;
            for (int t = 0; t < TT; ++t) aw[tid * TT + t] *= inv;
        }
        if (tid == 0) {
            int v = 0;
            for (int t = 0; t < TT; ++t) v |= mbuf[t];
            validf[g] = v ? 1.f : 0.f;
        }
        __syncthreads();

        // xbar[g][h][e] = sum_t aw[h][t] * x[t][e]   (thread = e, loop h)
        {
            int e = tid;
#pragma unroll
            for (int h = 0; h < HH; ++h) {
                float acc = 0.f;
#pragma unroll
                for (int t = 0; t < TT; ++t) acc += aw[h * TT + t] * xbuf[t * EE + e];
                xbar[g][h * EE + e] = acc;
            }
        }
    }
    __syncthreads();

    // ---------- Phase 2: ypre[g][j] = dot(Wv[j,:], xbar[g][head(j)]) + bv[j] ----------
    // wave w owns rows [64w, 64w+64) == head w. 4 rows at a time (16-lane groups).
    for (int rq = 0; rq < 16; ++rq) {
        int j = wave * 64 + rq * 4 + q4;
        const float* wrow = in_proj_w + (size_t)(2 * EE + j) * EE;  // Wv row j
        float wreg[16];
#pragma unroll
        for (int k = 0; k < 16; ++k) wreg[k] = wrow[li + 16 * k];
        float bvj = in_proj_b[2 * EE + j];
        for (int g = 0; g < GG; ++g) {
            const float* xb = &xbar[g][wave * EE];
            float part = 0.f;
#pragma unroll
            for (int k = 0; k < 16; ++k) part += wreg[k] * xb[li + 16 * k];
            float s = group16_reduce(part);
            if (li == 0) ypre[g][j] = s + bvj;
        }
    }
    __syncthreads();

    // ---------- Phase 3: outv[g][j] = dot(out_w[j,:], ypre[g][:]) + out_b[j] ----------
    for (int rq = 0; rq < 16; ++rq) {
        int j = wave * 64 + rq * 4 + q4;
        const float* wrow = out_w + (size_t)j * EE;
        float wreg[16];
#pragma unroll
        for (int k = 0; k < 16; ++k) wreg[k] = wrow[li + 16 * k];
        float bj = out_b[j];
        for (int g = 0; g < GG; ++g) {
            const float* yb = ypre[g];
            float part = 0.f;
#pragma unroll
            for (int k = 0; k < 16; ++k) part += wreg[k] * yb[li + 16 * k];
            float s = group16_reduce(part);
            if (li == 0) outv[g][j] = s + bj;
        }
    }
    __syncthreads();

    // ---------- Phase 4: LayerNorm per chunk; write into ypre (dead) ----------
    for (int gi = 0; gi < GG / 4; ++gi) {
        int g = wave + 4 * gi;
        float v0 = outv[g][lane], v1 = outv[g][lane + 64];
        float v2 = outv[g][lane + 128], v3 = outv[g][lane + 192];
        float mu = wave64_reduce(v0 + v1 + v2 + v3) * (1.0f / EE);
        float d0 = v0 - mu, d1 = v1 - mu, d2 = v2 - mu, d3 = v3 - mu;
        float var = wave64_reduce(d0 * d0 + d1 * d1 + d2 * d2 + d3 * d3) * (1.0f / EE);
        float rstd = rsqrtf(var + 1e-5f);
        ypre[g][lane]       = d0 * rstd * ln_g[lane]       + ln_b[lane];
        ypre[g][lane + 64]  = d1 * rstd * ln_g[lane + 64]  + ln_b[lane + 64];
        ypre[g][lane + 128] = d2 * rstd * ln_g[lane + 128] + ln_b[lane + 128];
        ypre[g][lane + 192] = d3 * rstd * ln_g[lane + 192] + ln_b[lane + 192];
    }
    __syncthreads();

    // ---------- Phase 5: MLP1 + exact gelu: hbuf[g][j] = gelu(dot(w1[j,:], hln) + b1[j]) ----------
    for (int rq = 0; rq < 8; ++rq) {
        int j = wave * 32 + rq * 4 + q4;   // 128 rows total
        const float* wrow = w1 + (size_t)j * EE;
        float wreg[16];
#pragma unroll
        for (int k = 0; k < 16; ++k) wreg[k] = wrow[li + 16 * k];
        float bj = b1[j];
        for (int g = 0; g < GG; ++g) {
            const float* yb = ypre[g];
            float part = 0.f;
#pragma unroll
            for (int k = 0; k < 16; ++k) part += wreg[k] * yb[li + 16 * k];
            float s = group16_reduce(part) + bj;
            float ge = 0.5f * s * (1.0f + erff(s * 0.70710678118654752f));
            if (li == 0) hbuf[g][j] = ge;
        }
    }
    __syncthreads();

    // ---------- Phase 6: logits[g] = dot(w2, hbuf[g]) + b2, masked by valid ----------
    for (int gi = 0; gi < GG / 4; ++gi) {
        int g = wave + 4 * gi;
        float part = w2[lane] * hbuf[g][lane] + w2[lane + 64] * hbuf[g][lane + 64];
        float s = wave64_reduce(part) + b2[0];
        if (lane == 0) out[chunk0 + g] = s * validf[g];
    }
}

extern "C" void kernel_launch(void* const* d_in, const int* in_sizes, int n_in,
                              void* d_out, int out_size, void* d_ws, size_t ws_size,
                              hipStream_t stream) {
    const float* x         = (const float*)d_in[0];
    const int*   mask      = (const int*)d_in[1];
    const float* query     = (const float*)d_in[2];
    const float* in_proj_w = (const float*)d_in[3];
    const float* in_proj_b = (const float*)d_in[4];
    const float* out_w     = (const float*)d_in[5];
    const float* out_b     = (const float*)d_in[6];
    const float* ln_g      = (const float*)d_in[7];
    const float* ln_b      = (const float*)d_in[8];
    const float* w1        = (const float*)d_in[9];
    const float* b1        = (const float*)d_in[10];
    const float* w2        = (const float*)d_in[11];
    const float* b2        = (const float*)d_in[12];
    float* out = (float*)d_out;

    float* s_w = (float*)d_ws;       // H*E floats
    float* s_b = s_w + HH * EE;      // H floats

    const int BN = out_size;         // 64*512 = 32768 chunks of T=6 tokens

    setup_kernel<<<1, NTHREADS, 0, stream>>>(query, in_proj_w, in_proj_b, s_w, s_b);
    fused_head_kernel<<<BN / GG, NTHREADS, 0, stream>>>(
        x, mask, in_proj_w, in_proj_b, out_w, out_b, ln_g, ln_b,
        w1, b1, w2, b2, s_w, s_b, out);
}

// Round 2
// 396.692 us; speedup vs baseline: 2.9620x; 2.9620x over previous
//
#include <hip/hip_runtime.h>
#include <math.h>

// B=64, N=512, T=6, H=4, E=256, hd=64 ; BN=32768 chunks
#define TT 6
#define HH 4
#define EE 256
#define RB 32            // chunks per block
#define PR 16            // chunks per phase-A pass
#define NTHREADS 256

typedef __attribute__((ext_vector_type(8))) short bf16x8;
typedef __attribute__((ext_vector_type(4))) float f32x4;

__device__ __forceinline__ unsigned short f2b(float f) {
    union { float f; unsigned u; } v; v.f = f;
    unsigned u = v.u + 0x7fffu + ((v.u >> 16) & 1u);
    return (unsigned short)(u >> 16);
}
__device__ __forceinline__ float b2f(unsigned short s) {
    union { unsigned u; float f; } v; v.u = ((unsigned)s) << 16;
    return v.f;
}

// ---------------- setup: parallel weight casts + query folding ----------------
// ws layout (bytes):
//   swt  [16][256] bf16   @ 0        (rows 4..15 zero)
//   sb   [4]  f32         @ 8192
//   wvb  [256][256] bf16  @ 8208
//   owb  [256][256] bf16  @ 139280
//   w1b  [128][256] bf16  @ 270352
#define SWT_OFF 0
#define SB_OFF  8192
#define WVB_OFF 8208
#define OWB_OFF 139280
#define W1B_OFF 270352

__global__ void setup_kernel(const float* __restrict__ query,
                             const float* __restrict__ in_proj_w,
                             const float* __restrict__ in_proj_b,
                             const float* __restrict__ out_w,
                             const float* __restrict__ w1,
                             unsigned char* __restrict__ ws)
{
    unsigned short* swt = (unsigned short*)(ws + SWT_OFF);
    float*          sb  = (float*)(ws + SB_OFF);
    unsigned short* wvb = (unsigned short*)(ws + WVB_OFF);
    unsigned short* owb = (unsigned short*)(ws + OWB_OFF);
    unsigned short* w1b = (unsigned short*)(ws + W1B_OFF);

    const int tid = threadIdx.x;
    const int gidx = blockIdx.x * NTHREADS + tid;
    const int gstride = gridDim.x * NTHREADS;

    for (int i = gidx; i < 65536; i += gstride) wvb[i] = f2b(in_proj_w[512 * 256 + i]);
    for (int i = gidx; i < 65536; i += gstride) owb[i] = f2b(out_w[i]);
    for (int i = gidx; i < 32768; i += gstride) w1b[i] = f2b(w1[i]);

    if (blockIdx.x == 0) {
        __shared__ float q[EE];
        // q[j] = query @ Wq[j,:] + bq[j]
        float acc = in_proj_b[tid];
        const float* row = in_proj_w + (size_t)tid * EE;
        for (int e = 0; e < EE; ++e) acc += query[e] * row[e];
        q[tid] = acc;
        __syncthreads();
        // swt[n][k] = sum_d q[n*64+d] * Wk[n*64+d][k]  (n<4; else 0)
        for (int i = 0; i < 16; ++i) {
            int flat = tid + NTHREADS * i;       // 4096 outputs
            int n = flat >> 8, k = flat & 255;
            float a = 0.f;
            if (n < HH) {
                for (int d = 0; d < 64; ++d)
                    a += q[n * 64 + d] * in_proj_w[(size_t)(EE + n * 64 + d) * EE + k];
            }
            swt[n * EE + k] = f2b(a);
        }
        if (tid < HH) {
            float a = 0.f;
            for (int d = 0; d < 64; ++d) a += q[tid * 64 + d] * in_proj_b[EE + tid * 64 + d];
            sb[tid] = a;
        }
    }
}

// ---------------- main fused kernel ----------------
// LDS pool layout (bytes):
#define XS_OFF   0                    // xs  [96][260] bf16 = 49920   (phase A; dead after)
#define XBT_OFF  49920                // xbt [32][1028] bf16 = 65792
#define SCF_OFF  115712               // scf [96][5] f32 = 1920
#define AW_OFF   117632               // aw4 [16][6][4] f32 = 1536
#define VAL_OFF  119168               // validf [32] f32 = 128
#define MB_OFF   119296               // mbuf [96] int = 384
#define POOL_SZ  119680
// aliases of the xs region after phase A:
#define YB_OFF   0                    // yb   [32][260] bf16 = 16640
#define OUTV_OFF 16640                // outv [32][260] f32  = 33280 (ends at 49920)
#define LNB_OFF  0                    // lnb  [32][260] bf16 (yb dead)
#define HB_OFF   16640                // hb   [32][136] bf16 (outv dead)

__global__ __launch_bounds__(NTHREADS, 1)
void fused_head_kernel(const float* __restrict__ x,
                       const int* __restrict__ mask,
                       const float* __restrict__ in_proj_b,
                       const float* __restrict__ out_b,
                       const float* __restrict__ ln_g,
                       const float* __restrict__ ln_b,
                       const float* __restrict__ b1,
                       const float* __restrict__ w2,
                       const float* __restrict__ b2,
                       const unsigned char* __restrict__ ws,
                       float* __restrict__ out)
{
    __shared__ __align__(16) unsigned char pool[POOL_SZ];
    unsigned short* xs   = (unsigned short*)(pool + XS_OFF);
    unsigned short* xbt  = (unsigned short*)(pool + XBT_OFF);
    float*          scf  = (float*)(pool + SCF_OFF);
    float*          aw4  = (float*)(pool + AW_OFF);
    float*          vldf = (float*)(pool + VAL_OFF);
    int*            mbuf = (int*)(pool + MB_OFF);
    unsigned short* yb   = (unsigned short*)(pool + YB_OFF);
    float*          outv = (float*)(pool + OUTV_OFF);
    unsigned short* lnb  = (unsigned short*)(pool + LNB_OFF);
    unsigned short* hb   = (unsigned short*)(pool + HB_OFF);

    const unsigned short* swt = (const unsigned short*)(ws + SWT_OFF);
    const float*          sb  = (const float*)(ws + SB_OFF);
    const unsigned short* wvb = (const unsigned short*)(ws + WVB_OFF);
    const unsigned short* owb = (const unsigned short*)(ws + OWB_OFF);
    const unsigned short* w1b = (const unsigned short*)(ws + W1B_OFF);

    const int tid = threadIdx.x;
    const int wv  = tid >> 6;
    const int ln  = tid & 63;
    const int qd  = ln >> 4;        // quad 0..3
    const int nl  = ln & 15;        // m/n lane 0..15
    const int chunk0 = blockIdx.x * RB;

    // ================= Phase A (two passes of 16 chunks) =================
    for (int p = 0; p < 2; ++p) {
        const int c0 = chunk0 + p * PR;
        __syncthreads();   // xs / mbuf / aw4 / scf reuse safe
        if (tid < PR * TT) mbuf[tid] = mask[(size_t)c0 * TT + tid];
        // ---- load x -> xs (bf16), 24576 floats
        const float* xp = x + (size_t)c0 * (TT * EE);
        for (int i = 0; i < 24; ++i) {
            int f = i * 1024 + tid * 4;
            float4 v = *(const float4*)(xp + f);
            int r = f >> 8, e = f & 255;
            union { unsigned short u[4]; uint2 v2; } t2;
            t2.u[0] = f2b(v.x); t2.u[1] = f2b(v.y);
            t2.u[2] = f2b(v.z); t2.u[3] = f2b(v.w);
            *(uint2*)(xs + r * 260 + e) = t2.v2;
        }
        __syncthreads();
        // ---- scores MFMA: S[(g,t)][h] = X @ swt^T ; 6 M-tiles over 96 rows
        for (int mt = wv; mt < 6; mt += 4) {
            f32x4 acc = {0.f, 0.f, 0.f, 0.f};
            for (int kb = 0; kb < EE; kb += 32) {
                bf16x8 a = *(const bf16x8*)(xs + (mt * 16 + nl) * 260 + kb + qd * 8);
                bf16x8 b = *(const bf16x8*)(swt + nl * EE + kb + qd * 8);
                acc = __builtin_amdgcn_mfma_f32_16x16x32_bf16(a, b, acc, 0, 0, 0);
            }
            if (nl < HH) {
#pragma unroll
                for (int i = 0; i < 4; ++i)
                    scf[(mt * 16 + qd * 4 + i) * 5 + nl] = acc[i];
            }
        }
        __syncthreads();
        // ---- softmax (one wave: lane -> (g,h))
        if (tid < 64) {
            int g = tid >> 2, h = tid & 3;
            const int* mrow = mbuf + g * TT;
            float sbh = sb[h];
            float vs[TT]; float m = -1e30f;
#pragma unroll
            for (int t = 0; t < TT; ++t) {
                float s = scf[(g * TT + t) * 5 + h] * 0.125f + sbh;
                s = mrow[t] ? s : -1e9f;
                vs[t] = s; m = fmaxf(m, s);
            }
            float sum = 0.f;
#pragma unroll
            for (int t = 0; t < TT; ++t) { float e = __expf(vs[t] - m); vs[t] = e; sum += e; }
            float inv = 1.f / sum;
#pragma unroll
            for (int t = 0; t < TT; ++t) aw4[(g * TT + t) * 4 + h] = vs[t] * inv;
            if (h == 0) {
                int vvv = 0;
#pragma unroll
                for (int t = 0; t < TT; ++t) vvv |= mrow[t];
                vldf[p * PR + g] = vvv ? 1.f : 0.f;
            }
        }
        __syncthreads();
        // ---- xbar (vector): thread handles 2 e-columns x 8 chunks
        {
            const int e  = (tid & 127) * 2;
            const int g0 = (tid >> 7) * 8;
            for (int gi = 0; gi < 8; ++gi) {
                int g = g0 + gi;
                float a0[HH] = {0.f, 0.f, 0.f, 0.f};
                float a1[HH] = {0.f, 0.f, 0.f, 0.f};
#pragma unroll
                for (int t = 0; t < TT; ++t) {
                    unsigned xp2 = *(const unsigned*)(xs + (g * TT + t) * 260 + e);
                    float x0 = b2f((unsigned short)(xp2 & 0xffffu));
                    float x1 = b2f((unsigned short)(xp2 >> 16));
                    float4 a = *(const float4*)(aw4 + (g * TT + t) * 4);
                    a0[0] += a.x * x0; a0[1] += a.y * x0; a0[2] += a.z * x0; a0[3] += a.w * x0;
                    a1[0] += a.x * x1; a1[1] += a.y * x1; a1[2] += a.z * x1; a1[3] += a.w * x1;
                }
                int grow = p * PR + g;
#pragma unroll
                for (int h = 0; h < HH; ++h) {
                    unsigned pk = (unsigned)f2b(a0[h]) | ((unsigned)f2b(a1[h]) << 16);
                    *(unsigned*)(xbt + grow * 1028 + h * EE + e) = pk;
                }
            }
        }
    }
    __syncthreads();

    // ================= Stage B1: ypre = blockdiag(Wv) @ xbar + bv =================
    {
        const int h = wv;                       // wave == head
        f32x4 acc[2][4];
#pragma unroll
        for (int mt = 0; mt < 2; ++mt)
#pragma unroll
            for (int nt = 0; nt < 4; ++nt) acc[mt][nt] = (f32x4){0.f, 0.f, 0.f, 0.f};
        for (int kb = 0; kb < EE; kb += 32) {
            bf16x8 a0 = *(const bf16x8*)(xbt + (nl)      * 1028 + h * EE + kb + qd * 8);
            bf16x8 a1 = *(const bf16x8*)(xbt + (16 + nl) * 1028 + h * EE + kb + qd * 8);
#pragma unroll
            for (int nt = 0; nt < 4; ++nt) {
                int j = h * 64 + nt * 16 + nl;
                bf16x8 b = *(const bf16x8*)(wvb + (size_t)j * EE + kb + qd * 8);
                acc[0][nt] = __builtin_amdgcn_mfma_f32_16x16x32_bf16(a0, b, acc[0][nt], 0, 0, 0);
                acc[1][nt] = __builtin_amdgcn_mfma_f32_16x16x32_bf16(a1, b, acc[1][nt], 0, 0, 0);
            }
        }
#pragma unroll
        for (int mt = 0; mt < 2; ++mt)
#pragma unroll
            for (int nt = 0; nt < 4; ++nt) {
                int j = h * 64 + nt * 16 + nl;
                float bvj = in_proj_b[2 * EE + j];
#pragma unroll
                for (int i = 0; i < 4; ++i)
                    yb[(mt * 16 + qd * 4 + i) * 260 + j] = f2b(acc[mt][nt][i] + bvj);
            }
    }
    __syncthreads();

    // ================= Stage B2: outv = out_w @ ypre + out_b =================
    {
        f32x4 acc[2][4];
#pragma unroll
        for (int mt = 0; mt < 2; ++mt)
#pragma unroll
            for (int nt = 0; nt < 4; ++nt) acc[mt][nt] = (f32x4){0.f, 0.f, 0.f, 0.f};
        for (int kb = 0; kb < EE; kb += 32) {
            bf16x8 a0 = *(const bf16x8*)(yb + (nl)      * 260 + kb + qd * 8);
            bf16x8 a1 = *(const bf16x8*)(yb + (16 + nl) * 260 + kb + qd * 8);
#pragma unroll
            for (int nt = 0; nt < 4; ++nt) {
                int j = wv * 64 + nt * 16 + nl;
                bf16x8 b = *(const bf16x8*)(owb + (size_t)j * EE + kb + qd * 8);
                acc[0][nt] = __builtin_amdgcn_mfma_f32_16x16x32_bf16(a0, b, acc[0][nt], 0, 0, 0);
                acc[1][nt] = __builtin_amdgcn_mfma_f32_16x16x32_bf16(a1, b, acc[1][nt], 0, 0, 0);
            }
        }
        __syncthreads();   // yb dead only after all waves finish reading
#pragma unroll
        for (int mt = 0; mt < 2; ++mt)
#pragma unroll
            for (int nt = 0; nt < 4; ++nt) {
                int j = wv * 64 + nt * 16 + nl;
                float obj = out_b[j];
#pragma unroll
                for (int i = 0; i < 4; ++i)
                    outv[(mt * 16 + qd * 4 + i) * 260 + j] = acc[mt][nt][i] + obj;
            }
    }
    __syncthreads();

    // ================= Stage C: LayerNorm -> lnb (bf16) =================
    {
        int g = tid >> 3, kc = tid & 7;
        float vals[32];
        float s = 0.f, ss = 0.f;
#pragma unroll
        for (int i = 0; i < 8; ++i) {
            float4 v = *(const float4*)(outv + g * 260 + kc * 32 + i * 4);
            vals[i * 4 + 0] = v.x; vals[i * 4 + 1] = v.y;
            vals[i * 4 + 2] = v.z; vals[i * 4 + 3] = v.w;
            s += v.x + v.y + v.z + v.w;
            ss += v.x * v.x + v.y * v.y + v.z * v.z + v.w * v.w;
        }
#pragma unroll
        for (int d = 4; d; d >>= 1) { s += __shfl_xor(s, d, 64); ss += __shfl_xor(ss, d, 64); }
        float mu = s * (1.f / EE);
        float var = ss * (1.f / EE) - mu * mu;
        float rstd = rsqrtf(var + 1e-5f);
#pragma unroll
        for (int i = 0; i < 32; i += 2) {
            int j = kc * 32 + i;
            float2 gg = *(const float2*)(ln_g + j);
            float2 bb = *(const float2*)(ln_b + j);
            float o0 = (vals[i]     - mu) * rstd * gg.x + bb.x;
            float o1 = (vals[i + 1] - mu) * rstd * gg.y + bb.y;
            unsigned pk = (unsigned)f2b(o0) | ((unsigned)f2b(o1) << 16);
            *(unsigned*)(lnb + g * 260 + j) = pk;
        }
    }
    __syncthreads();

    // ================= Stage D: h = gelu(ln @ w1^T + b1) -> hb (bf16) =================
    {
        f32x4 acc[2][2];
#pragma unroll
        for (int mt = 0; mt < 2; ++mt)
#pragma unroll
            for (int nt = 0; nt < 2; ++nt) acc[mt][nt] = (f32x4){0.f, 0.f, 0.f, 0.f};
        for (int kb = 0; kb < EE; kb += 32) {
            bf16x8 a0 = *(const bf16x8*)(lnb + (nl)      * 260 + kb + qd * 8);
            bf16x8 a1 = *(const bf16x8*)(lnb + (16 + nl) * 260 + kb + qd * 8);
#pragma unroll
            for (int nt = 0; nt < 2; ++nt) {
                int j = wv * 32 + nt * 16 + nl;
                bf16x8 b = *(const bf16x8*)(w1b + (size_t)j * EE + kb + qd * 8);
                acc[0][nt] = __builtin_amdgcn_mfma_f32_16x16x32_bf16(a0, b, acc[0][nt], 0, 0, 0);
                acc[1][nt] = __builtin_amdgcn_mfma_f32_16x16x32_bf16(a1, b, acc[1][nt], 0, 0, 0);
            }
        }
        __syncthreads();   // outv region about to be overwritten by hb
#pragma unroll
        for (int mt = 0; mt < 2; ++mt)
#pragma unroll
            for (int nt = 0; nt < 2; ++nt) {
                int j = wv * 32 + nt * 16 + nl;
                float bj = b1[j];
#pragma unroll
                for (int i = 0; i < 4; ++i) {
                    float sv = acc[mt][nt][i] + bj;
                    float ge = 0.5f * sv * (1.0f + erff(sv * 0.70710678118654752f));
                    hb[(mt * 16 + qd * 4 + i) * 136 + j] = f2b(ge);
                }
            }
    }
    __syncthreads();

    // ================= Stage E: logits = h @ w2 + b2, masked =================
    {
        int g = tid >> 3, j0 = (tid & 7) * 16;
        float part = 0.f;
#pragma unroll
        for (int i = 0; i < 16; i += 2) {
            unsigned pk = *(const unsigned*)(hb + g * 136 + j0 + i);
            float h0 = b2f((unsigned short)(pk & 0xffffu));
            float h1 = b2f((unsigned short)(pk >> 16));
            float2 ww = *(const float2*)(w2 + j0 + i);
            part += ww.x * h0 + ww.y * h1;
        }
#pragma unroll
        for (int d = 4; d; d >>= 1) part += __shfl_xor(part, d, 64);
        if ((tid & 7) == 0) out[chunk0 + g] = (part + b2[0]) * vldf[g];
    }
}

extern "C" void kernel_launch(void* const* d_in, const int* in_sizes, int n_in,
                              void* d_out, int out_size, void* d_ws, size_t ws_size,
                              hipStream_t stream) {
    const float* x         = (const float*)d_in[0];
    const int*   mask      = (const int*)d_in[1];
    const float* query     = (const float*)d_in[2];
    const float* in_proj_w = (const float*)d_in[3];
    const float* in_proj_b = (const float*)d_in[4];
    const float* out_w     = (const float*)d_in[5];
    const float* out_b     = (const float*)d_in[6];
    const float* ln_g      = (const float*)d_in[7];
    const float* ln_b      = (const float*)d_in[8];
    const float* w1        = (const float*)d_in[9];
    const float* b1        = (const float*)d_in[10];
    const float* w2        = (const float*)d_in[11];
    const float* b2        = (const float*)d_in[12];
    float* out = (float*)d_out;
    unsigned char* ws = (unsigned char*)d_ws;

    const int BN = out_size;                  // 32768

    setup_kernel<<<128, NTHREADS, 0, stream>>>(query, in_proj_w, in_proj_b, out_w, w1, ws);
    fused_head_kernel<<<BN / RB, NTHREADS, 0, stream>>>(
        x, mask, in_proj_b, out_b, ln_g, ln_b, b1, w2, b2, ws, out);
}

// Round 3
// 394.793 us; speedup vs baseline: 2.9762x; 1.0048x over previous
//
#include <hip/hip_runtime.h>
#include <math.h>

// B=64, N=512, T=6, H=4, E=256, hd=64 ; BN=32768 chunks
#define TT 6
#define HH 4
#define EE 256
#define RB 16            // chunks per block
#define PR 8             // chunks per phase-A pass
#define NTHREADS 256

typedef __attribute__((ext_vector_type(8))) short bf16x8;
typedef __attribute__((ext_vector_type(4))) float f32x4;

__device__ __forceinline__ unsigned short f2b(float f) {
    union { float f; unsigned u; } v; v.f = f;
    unsigned u = v.u + 0x7fffu + ((v.u >> 16) & 1u);
    return (unsigned short)(u >> 16);
}
__device__ __forceinline__ float b2f(unsigned short s) {
    union { unsigned u; float f; } v; v.u = ((unsigned)s) << 16;
    return v.f;
}

// ---------------- workspace layout (bytes) ----------------
//   swt  [16][256] bf16   @ 0        (rows 4..15 zero)
//   sb   [4]  f32         @ 8192
//   qv   [256] f32        @ 8208
//   wvb  [256][256] bf16  @ 9232
//   owb  [256][256] bf16  @ 140304
//   w1b  [128][256] bf16  @ 271376   (ends 336912)
#define SWT_OFF 0
#define SB_OFF  8192
#define Q_OFF   8208
#define WVB_OFF 9232
#define OWB_OFF 140304
#define W1B_OFF 271376

// ---- setup 1: q = query @ Wq^T + bq ; sb[h] = q_h . bk_h  (1 block) ----
__global__ void setup_q(const float* __restrict__ query,
                        const float* __restrict__ in_proj_w,
                        const float* __restrict__ in_proj_b,
                        unsigned char* __restrict__ ws)
{
    __shared__ float qs[EE];
    float* qv = (float*)(ws + Q_OFF);
    float* sb = (float*)(ws + SB_OFF);
    const int tid = threadIdx.x;
    float acc = in_proj_b[tid];
    const float* row = in_proj_w + (size_t)tid * EE;
    for (int e = 0; e < EE; e += 4) {
        float4 w = *(const float4*)(row + e);
        float4 q = *(const float4*)(query + e);
        acc += w.x * q.x + w.y * q.y + w.z * q.z + w.w * q.w;
    }
    qs[tid] = acc;
    qv[tid] = acc;
    __syncthreads();
    if (tid < HH) {
        float a = 0.f;
        for (int d = 0; d < 64; ++d) a += qs[tid * 64 + d] * in_proj_b[EE + tid * 64 + d];
        sb[tid] = a;
    }
}

// ---- setup 2: weight casts (grid-stride) + swt fold (blocks 0..4) ----
__global__ void setup_cast(const float* __restrict__ in_proj_w,
                           const float* __restrict__ out_w,
                           const float* __restrict__ w1,
                           unsigned char* __restrict__ ws)
{
    unsigned short* swt = (unsigned short*)(ws + SWT_OFF);
    const float*    qv  = (const float*)(ws + Q_OFF);
    unsigned short* wvb = (unsigned short*)(ws + WVB_OFF);
    unsigned short* owb = (unsigned short*)(ws + OWB_OFF);
    unsigned short* w1b = (unsigned short*)(ws + W1B_OFF);

    const int tid = threadIdx.x;
    const int gidx = blockIdx.x * NTHREADS + tid;
    const int gstride = gridDim.x * NTHREADS;

    for (int i = gidx; i < 65536; i += gstride) wvb[i] = f2b(in_proj_w[512 * 256 + i]);
    for (int i = gidx; i < 65536; i += gstride) owb[i] = f2b(out_w[i]);
    for (int i = gidx; i < 32768; i += gstride) w1b[i] = f2b(w1[i]);

    if (blockIdx.x < HH) {
        // swt[n][k] = sum_d q[n*64+d] * Wk[n*64+d][k]
        const int n = blockIdx.x;
        float a = 0.f;
        for (int d = 0; d < 64; ++d)
            a += qv[n * 64 + d] * in_proj_w[(size_t)(EE + n * 64 + d) * EE + tid];
        swt[n * EE + tid] = f2b(a);
    } else if (blockIdx.x == HH) {
        for (int i = HH * EE + tid; i < 16 * EE; i += NTHREADS) swt[i] = 0;
    }
}

// ---------------- main fused kernel ----------------
// LDS pool layout (bytes):
#define XS_OFF   0                    // xs  [48][260] bf16 = 24960  (phase A; dead after)
#define XBT_OFF  24960                // xbt [16][1028] bf16 = 32896
#define SCF_OFF  57856                // scf [48][5] f32 = 960
#define AW_OFF   58816                // aw4 [8][6][4] f32 = 768
#define VAL_OFF  59584                // validf [16] f32 = 64
#define MB_OFF   59648                // mbuf [48] int = 192
#define POOL_SZ  59840
// aliases of the xs region after phase A:
#define YB_OFF   0                    // yb   [16][260] bf16 = 8320
#define OUTV_OFF 8320                 // outv [16][260] f32  = 16640 (ends 24960)
#define LNB_OFF  0                    // lnb  [16][260] bf16 (yb dead)
#define HB_OFF   8320                 // hb   [16][136] bf16 (outv dead)

__global__ __launch_bounds__(NTHREADS, 2)
void fused_head_kernel(const float* __restrict__ x,
                       const int* __restrict__ mask,
                       const float* __restrict__ in_proj_b,
                       const float* __restrict__ out_b,
                       const float* __restrict__ ln_g,
                       const float* __restrict__ ln_b,
                       const float* __restrict__ b1,
                       const float* __restrict__ w2,
                       const float* __restrict__ b2,
                       const unsigned char* __restrict__ ws,
                       float* __restrict__ out)
{
    __shared__ __align__(16) unsigned char pool[POOL_SZ];
    unsigned short* xs   = (unsigned short*)(pool + XS_OFF);
    unsigned short* xbt  = (unsigned short*)(pool + XBT_OFF);
    float*          scf  = (float*)(pool + SCF_OFF);
    float*          aw4  = (float*)(pool + AW_OFF);
    float*          vldf = (float*)(pool + VAL_OFF);
    int*            mbuf = (int*)(pool + MB_OFF);
    unsigned short* yb   = (unsigned short*)(pool + YB_OFF);
    float*          outv = (float*)(pool + OUTV_OFF);
    unsigned short* lnb  = (unsigned short*)(pool + LNB_OFF);
    unsigned short* hb   = (unsigned short*)(pool + HB_OFF);

    const unsigned short* swt = (const unsigned short*)(ws + SWT_OFF);
    const float*          sb  = (const float*)(ws + SB_OFF);
    const unsigned short* wvb = (const unsigned short*)(ws + WVB_OFF);
    const unsigned short* owb = (const unsigned short*)(ws + OWB_OFF);
    const unsigned short* w1b = (const unsigned short*)(ws + W1B_OFF);

    const int tid = threadIdx.x;
    const int wv  = tid >> 6;
    const int ln  = tid & 63;
    const int qd  = ln >> 4;        // quad 0..3
    const int nl  = ln & 15;        // m/n lane 0..15
    const int chunk0 = blockIdx.x * RB;

    // ================= Phase A (two passes of 8 chunks) =================
    for (int p = 0; p < 2; ++p) {
        const int c0 = chunk0 + p * PR;
        __syncthreads();   // xs / mbuf / aw4 / scf reuse safe
        if (tid < PR * TT) mbuf[tid] = mask[(size_t)c0 * TT + tid];
        // ---- load x -> xs (bf16), 12288 floats
        const float* xp = x + (size_t)c0 * (TT * EE);
        for (int i = 0; i < 12; ++i) {
            int f = i * 1024 + tid * 4;
            float4 v = *(const float4*)(xp + f);
            int r = f >> 8, e = f & 255;
            union { unsigned short u[4]; uint2 v2; } t2;
            t2.u[0] = f2b(v.x); t2.u[1] = f2b(v.y);
            t2.u[2] = f2b(v.z); t2.u[3] = f2b(v.w);
            *(uint2*)(xs + r * 260 + e) = t2.v2;
        }
        __syncthreads();
        // ---- scores MFMA: S[(g,t)][h] = X @ swt^T ; 3 M-tiles over 48 rows
        if (wv < 3) {
            const int mt = wv;
            f32x4 acc = {0.f, 0.f, 0.f, 0.f};
            for (int kb = 0; kb < EE; kb += 32) {
                bf16x8 a = *(const bf16x8*)(xs + (mt * 16 + nl) * 260 + kb + qd * 8);
                bf16x8 b = *(const bf16x8*)(swt + nl * EE + kb + qd * 8);
                acc = __builtin_amdgcn_mfma_f32_16x16x32_bf16(a, b, acc, 0, 0, 0);
            }
            if (nl < HH) {
#pragma unroll
                for (int i = 0; i < 4; ++i)
                    scf[(mt * 16 + qd * 4 + i) * 5 + nl] = acc[i];
            }
        }
        __syncthreads();
        // ---- softmax (tid<32: (g,h))
        if (tid < PR * HH) {
            int g = tid >> 2, h = tid & 3;
            const int* mrow = mbuf + g * TT;
            float sbh = sb[h];
            float vs[TT]; float m = -1e30f;
#pragma unroll
            for (int t = 0; t < TT; ++t) {
                float s = scf[(g * TT + t) * 5 + h] * 0.125f + sbh;
                s = mrow[t] ? s : -1e9f;
                vs[t] = s; m = fmaxf(m, s);
            }
            float sum = 0.f;
#pragma unroll
            for (int t = 0; t < TT; ++t) { float e = __expf(vs[t] - m); vs[t] = e; sum += e; }
            float inv = 1.f / sum;
#pragma unroll
            for (int t = 0; t < TT; ++t) aw4[(g * TT + t) * 4 + h] = vs[t] * inv;
            if (h == 0) {
                int vvv = 0;
#pragma unroll
                for (int t = 0; t < TT; ++t) vvv |= mrow[t];
                vldf[p * PR + g] = vvv ? 1.f : 0.f;
            }
        }
        __syncthreads();
        // ---- xbar (vector): thread handles 2 e-columns x 4 chunks
        {
            const int e  = (tid & 127) * 2;
            const int g0 = (tid >> 7) * 4;
            for (int gi = 0; gi < 4; ++gi) {
                int g = g0 + gi;
                float a0[HH] = {0.f, 0.f, 0.f, 0.f};
                float a1[HH] = {0.f, 0.f, 0.f, 0.f};
#pragma unroll
                for (int t = 0; t < TT; ++t) {
                    unsigned xp2 = *(const unsigned*)(xs + (g * TT + t) * 260 + e);
                    float x0 = b2f((unsigned short)(xp2 & 0xffffu));
                    float x1 = b2f((unsigned short)(xp2 >> 16));
                    float4 a = *(const float4*)(aw4 + (g * TT + t) * 4);
                    a0[0] += a.x * x0; a0[1] += a.y * x0; a0[2] += a.z * x0; a0[3] += a.w * x0;
                    a1[0] += a.x * x1; a1[1] += a.y * x1; a1[2] += a.z * x1; a1[3] += a.w * x1;
                }
                int grow = p * PR + g;
#pragma unroll
                for (int h = 0; h < HH; ++h) {
                    unsigned pk = (unsigned)f2b(a0[h]) | ((unsigned)f2b(a1[h]) << 16);
                    *(unsigned*)(xbt + grow * 1028 + h * EE + e) = pk;
                }
            }
        }
    }
    __syncthreads();

    // ================= Stage B1: ypre = blockdiag(Wv) @ xbar + bv  (M=16) =================
    {
        const int h = wv;                       // wave == head
        f32x4 acc[4];
#pragma unroll
        for (int nt = 0; nt < 4; ++nt) acc[nt] = (f32x4){0.f, 0.f, 0.f, 0.f};
        for (int kb = 0; kb < EE; kb += 32) {
            bf16x8 a = *(const bf16x8*)(xbt + nl * 1028 + h * EE + kb + qd * 8);
#pragma unroll
            for (int nt = 0; nt < 4; ++nt) {
                int j = h * 64 + nt * 16 + nl;
                bf16x8 b = *(const bf16x8*)(wvb + (size_t)j * EE + kb + qd * 8);
                acc[nt] = __builtin_amdgcn_mfma_f32_16x16x32_bf16(a, b, acc[nt], 0, 0, 0);
            }
        }
#pragma unroll
        for (int nt = 0; nt < 4; ++nt) {
            int j = h * 64 + nt * 16 + nl;
            float bvj = in_proj_b[2 * EE + j];
#pragma unroll
            for (int i = 0; i < 4; ++i)
                yb[(qd * 4 + i) * 260 + j] = f2b(acc[nt][i] + bvj);
        }
    }
    __syncthreads();

    // ================= Stage B2: outv = out_w @ ypre + out_b  (M=16) =================
    {
        f32x4 acc[4];
#pragma unroll
        for (int nt = 0; nt < 4; ++nt) acc[nt] = (f32x4){0.f, 0.f, 0.f, 0.f};
        for (int kb = 0; kb < EE; kb += 32) {
            bf16x8 a = *(const bf16x8*)(yb + nl * 260 + kb + qd * 8);
#pragma unroll
            for (int nt = 0; nt < 4; ++nt) {
                int j = wv * 64 + nt * 16 + nl;
                bf16x8 b = *(const bf16x8*)(owb + (size_t)j * EE + kb + qd * 8);
                acc[nt] = __builtin_amdgcn_mfma_f32_16x16x32_bf16(a, b, acc[nt], 0, 0, 0);
            }
        }
        // outv region disjoint from yb; writes race with nothing
#pragma unroll
        for (int nt = 0; nt < 4; ++nt) {
            int j = wv * 64 + nt * 16 + nl;
            float obj = out_b[j];
#pragma unroll
            for (int i = 0; i < 4; ++i)
                outv[(qd * 4 + i) * 260 + j] = acc[nt][i] + obj;
        }
    }
    __syncthreads();

    // ================= Stage C: LayerNorm -> lnb (bf16, over yb region) =================
    {
        int g = tid >> 4, kc = tid & 15;
        float vals[16];
        float s = 0.f, ss = 0.f;
#pragma unroll
        for (int i = 0; i < 4; ++i) {
            float4 v = *(const float4*)(outv + g * 260 + kc * 16 + i * 4);
            vals[i * 4 + 0] = v.x; vals[i * 4 + 1] = v.y;
            vals[i * 4 + 2] = v.z; vals[i * 4 + 3] = v.w;
            s += v.x + v.y + v.z + v.w;
            ss += v.x * v.x + v.y * v.y + v.z * v.z + v.w * v.w;
        }
#pragma unroll
        for (int d = 8; d; d >>= 1) { s += __shfl_xor(s, d, 64); ss += __shfl_xor(ss, d, 64); }
        float mu = s * (1.f / EE);
        float var = ss * (1.f / EE) - mu * mu;
        float rstd = rsqrtf(var + 1e-5f);
#pragma unroll
        for (int i = 0; i < 16; i += 2) {
            int j = kc * 16 + i;
            float2 gg = *(const float2*)(ln_g + j);
            float2 bb = *(const float2*)(ln_b + j);
            float o0 = (vals[i]     - mu) * rstd * gg.x + bb.x;
            float o1 = (vals[i + 1] - mu) * rstd * gg.y + bb.y;
            unsigned pk = (unsigned)f2b(o0) | ((unsigned)f2b(o1) << 16);
            *(unsigned*)(lnb + g * 260 + j) = pk;
        }
    }
    __syncthreads();

    // ================= Stage D: h = gelu(ln @ w1^T + b1) -> hb (over outv region) =================
    {
        f32x4 acc[2];
#pragma unroll
        for (int nt = 0; nt < 2; ++nt) acc[nt] = (f32x4){0.f, 0.f, 0.f, 0.f};
        for (int kb = 0; kb < EE; kb += 32) {
            bf16x8 a = *(const bf16x8*)(lnb + nl * 260 + kb + qd * 8);
#pragma unroll
            for (int nt = 0; nt < 2; ++nt) {
                int j = wv * 32 + nt * 16 + nl;
                bf16x8 b = *(const bf16x8*)(w1b + (size_t)j * EE + kb + qd * 8);
                acc[nt] = __builtin_amdgcn_mfma_f32_16x16x32_bf16(a, b, acc[nt], 0, 0, 0);
            }
        }
#pragma unroll
        for (int nt = 0; nt < 2; ++nt) {
            int j = wv * 32 + nt * 16 + nl;
            float bj = b1[j];
#pragma unroll
            for (int i = 0; i < 4; ++i) {
                float sv = acc[nt][i] + bj;
                float ge = 0.5f * sv * (1.0f + erff(sv * 0.70710678118654752f));
                hb[(qd * 4 + i) * 136 + j] = f2b(ge);
            }
        }
    }
    __syncthreads();

    // ================= Stage E: logits = h @ w2 + b2, masked =================
    {
        int g = tid >> 4, j0 = (tid & 15) * 8;
        float part = 0.f;
#pragma unroll
        for (int i = 0; i < 8; i += 2) {
            unsigned pk = *(const unsigned*)(hb + g * 136 + j0 + i);
            float h0 = b2f((unsigned short)(pk & 0xffffu));
            float h1 = b2f((unsigned short)(pk >> 16));
            float2 ww = *(const float2*)(w2 + j0 + i);
            part += ww.x * h0 + ww.y * h1;
        }
#pragma unroll
        for (int d = 8; d; d >>= 1) part += __shfl_xor(part, d, 64);
        if ((tid & 15) == 0) out[chunk0 + g] = (part + b2[0]) * vldf[g];
    }
}

extern "C" void kernel_launch(void* const* d_in, const int* in_sizes, int n_in,
                              void* d_out, int out_size, void* d_ws, size_t ws_size,
                              hipStream_t stream) {
    const float* x         = (const float*)d_in[0];
    const int*   mask      = (const int*)d_in[1];
    const float* query     = (const float*)d_in[2];
    const float* in_proj_w = (const float*)d_in[3];
    const float* in_proj_b = (const float*)d_in[4];
    const float* out_w     = (const float*)d_in[5];
    const float* out_b     = (const float*)d_in[6];
    const float* ln_g      = (const float*)d_in[7];
    const float* ln_b      = (const float*)d_in[8];
    const float* w1        = (const float*)d_in[9];
    const float* b1        = (const float*)d_in[10];
    const float* w2        = (const float*)d_in[11];
    const float* b2        = (const float*)d_in[12];
    float* out = (float*)d_out;
    unsigned char* ws = (unsigned char*)d_ws;

    const int BN = out_size;                  // 32768

    setup_q<<<1, NTHREADS, 0, stream>>>(query, in_proj_w, in_proj_b, ws);
    setup_cast<<<128, NTHREADS, 0, stream>>>(in_proj_w, out_w, w1, ws);
    fused_head_kernel<<<BN / RB, NTHREADS, 0, stream>>>(
        x, mask, in_proj_b, out_b, ln_g, ln_b, b1, w2, b2, ws, out);
}